// Round 6
// baseline (248.091 us; speedup 1.0000x reference)
//
#include <hip/hip_runtime.h>
#include <hip/hip_bf16.h>

#define B_ 2
#define S_ 2048
#define D_ 768
#define H_ 12
#define DH_ 64
#define M_ (B_*S_)     // 4096
#define BH_ (B_*H_)    // 24

typedef __bf16 v8bf __attribute__((ext_vector_type(8)));
typedef __bf16 v4bf __attribute__((ext_vector_type(4)));
typedef float  v4f  __attribute__((ext_vector_type(4)));
typedef float  f32x16 __attribute__((ext_vector_type(16)));

static __device__ __forceinline__ v4f mfma16(v8bf a, v8bf b, v4f c) {
  return __builtin_amdgcn_mfma_f32_16x16x32_bf16(a, b, c, 0, 0, 0);
}
static __device__ __forceinline__ f32x16 mfma32(v8bf a, v8bf b, f32x16 c) {
  return __builtin_amdgcn_mfma_f32_32x32x16_bf16(a, b, c, 0, 0, 0);
}

// async global->LDS, 16 B/lane; dest = wave-uniform base + lane*16
static __device__ __forceinline__ void gload_lds16(const __bf16* g, __bf16* l) {
  __builtin_amdgcn_global_load_lds(
      (const __attribute__((address_space(1))) unsigned int*)g,
      (__attribute__((address_space(3))) unsigned int*)l,
      16, 0, 0);
}

#define C1_ 0.18033688011112042f   // log2(e)/sqrt(DH)

// ---------------- fp32 -> bf16 conversion ----------------
__global__ __launch_bounds__(256) void convert_kernel(
    const float* __restrict__ q, const float* __restrict__ k, const float* __restrict__ v,
    const float* __restrict__ Wq, const float* __restrict__ Wk,
    const float* __restrict__ Wv, const float* __restrict__ Wo,
    __bf16* __restrict__ Xq, __bf16* __restrict__ Xk, __bf16* __restrict__ Xv,
    __bf16* __restrict__ Wqb, __bf16* __restrict__ Wkb,
    __bf16* __restrict__ Wvb, __bf16* __restrict__ Wob)
{
  const float* src; __bf16* dst; int n;
  switch (blockIdx.y) {
    case 0: src = q;  dst = Xq;  n = M_*D_; break;
    case 1: src = k;  dst = Xk;  n = M_*D_; break;
    case 2: src = v;  dst = Xv;  n = M_*D_; break;
    case 3: src = Wq; dst = Wqb; n = D_*D_; break;
    case 4: src = Wk; dst = Wkb; n = D_*D_; break;
    case 5: src = Wv; dst = Wvb; n = D_*D_; break;
    default: src = Wo; dst = Wob; n = D_*D_; break;
  }
  int n4 = n >> 2;
  for (int i = blockIdx.x*blockDim.x + threadIdx.x; i < n4; i += gridDim.x*blockDim.x) {
    float4 x = ((const float4*)src)[i];
    v4bf y;
    y[0] = (__bf16)x.x; y[1] = (__bf16)x.y; y[2] = (__bf16)x.z; y[3] = (__bf16)x.w;
    ((v4bf*)dst)[i] = y;
  }
}

// ---------------- em precompute for 32x32 fragment order ----------------
// t = ((qt*64 + kt)*4 + w)*64 + L  (t < 262144); elem t*16 + r (r=0..15) holds
// exp2(C1*mask[qt*128 + w*32 + (L&31)][kt*32 + 4*(L>>5) + (r&3) + 8*(r>>2)])
// matching the 32x32 C/D layout: col(q)=lane&31, row(key)=(r&3)+8*(r>>2)+4*(lane>>5).
__global__ __launch_bounds__(256) void em_kernel(
    const float* __restrict__ mask, __bf16* __restrict__ em)
{
  int t = blockIdx.x*256 + threadIdx.x;        // 0 .. 262143  (grid = 1024 blocks!)
  int L = t & 63; int rest = t >> 6;
  int w = rest & 3; rest >>= 2;
  int kt = rest & 63; rest >>= 6;
  int qt = rest;                                // 0..15
  int row = qt*128 + w*32 + (L & 31);
  int key0 = kt*32 + ((L >> 5) << 2);
  const float* mp = mask + (size_t)row*S_ + key0;
  float4 m0 = *(const float4*)(mp);        // keys +0..3
  float4 m1 = *(const float4*)(mp + 8);    // keys +8..11
  float4 m2 = *(const float4*)(mp + 16);   // keys +16..19
  float4 m3 = *(const float4*)(mp + 24);   // keys +24..27
  v8bf e0, e1;
  e0[0] = (__bf16)exp2f(C1_*m0.x); e0[1] = (__bf16)exp2f(C1_*m0.y);
  e0[2] = (__bf16)exp2f(C1_*m0.z); e0[3] = (__bf16)exp2f(C1_*m0.w);
  e0[4] = (__bf16)exp2f(C1_*m1.x); e0[5] = (__bf16)exp2f(C1_*m1.y);
  e0[6] = (__bf16)exp2f(C1_*m1.z); e0[7] = (__bf16)exp2f(C1_*m1.w);
  e1[0] = (__bf16)exp2f(C1_*m2.x); e1[1] = (__bf16)exp2f(C1_*m2.y);
  e1[2] = (__bf16)exp2f(C1_*m2.z); e1[3] = (__bf16)exp2f(C1_*m2.w);
  e1[4] = (__bf16)exp2f(C1_*m3.x); e1[5] = (__bf16)exp2f(C1_*m3.y);
  e1[6] = (__bf16)exp2f(C1_*m3.z); e1[7] = (__bf16)exp2f(C1_*m3.w);
  *(v8bf*)(em + (size_t)t*16)     = e0;
  *(v8bf*)(em + (size_t)t*16 + 8) = e1;
}

// ---------------- 128x128 NT-GEMM core, counted-vmcnt 3-buffer pipeline ----------------
static __device__ __forceinline__ void gemm128_pipe(
    const __bf16* __restrict__ A, const __bf16* __restrict__ W,
    int m0, int n0, __bf16* lds, v4f acc[4][4])
{
  const int lane = threadIdx.x & 63;
  const int wave = threadIdx.x >> 6;
  const int r16 = lane & 15;
  const int kc8 = (lane >> 4) << 3;
  const int ia = (wave >> 1) << 2;
  const int ib = (wave & 1) << 2;

  const __bf16* gsrc[4]; int ldo[4];
  #pragma unroll
  for (int t = 0; t < 4; t++) {
    int fb = wave*4 + t;
    gsrc[t] = (fb < 8)
        ? A + (size_t)(m0 + fb*16 + r16)*D_ + kc8
        : W + (size_t)(n0 + (fb - 8)*16 + r16)*D_ + kc8;
    ldo[t] = fb << 9;
  }

  asm volatile("" ::: "memory");
  #pragma unroll
  for (int t = 0; t < 4; t++) gload_lds16(gsrc[t], lds + ldo[t]);
  asm volatile("" ::: "memory");
  #pragma unroll
  for (int t = 0; t < 4; t++) gload_lds16(gsrc[t] + 32, lds + 8192 + ldo[t]);
  asm volatile("" ::: "memory");

#define G_STEP(CUR, NXTB, KC, ISSUE, WSTR) { \
    asm volatile("s_waitcnt vmcnt(" WSTR ")" ::: "memory"); \
    __builtin_amdgcn_s_barrier(); \
    asm volatile("" ::: "memory"); \
    if (ISSUE) { \
      _Pragma("unroll") \
      for (int t = 0; t < 4; t++) \
        gload_lds16(gsrc[t] + (KC), lds + (NXTB)*8192 + ldo[t]); \
    } \
    const __bf16* buf = lds + (CUR)*8192; \
    v8bf a[4], b[4]; \
    _Pragma("unroll") \
    for (int i = 0; i < 4; i++) a[i] = *(const v8bf*)(buf + ((ia+i) << 9) + lane*8); \
    _Pragma("unroll") \
    for (int j = 0; j < 4; j++) b[j] = *(const v8bf*)(buf + ((8+ib+j) << 9) + lane*8); \
    _Pragma("unroll") \
    for (int i = 0; i < 4; i++) \
      _Pragma("unroll") \
      for (int j = 0; j < 4; j++) \
        acc[i][j] = mfma16(a[i], b[j], acc[i][j]); \
  }

  #pragma unroll 1
  for (int ks0 = 0; ks0 < 18; ks0 += 3) {
    G_STEP(0, 2, (ks0+2)*32, true, "4");
    G_STEP(1, 0, (ks0+3)*32, true, "4");
    G_STEP(2, 1, (ks0+4)*32, true, "4");
  }
  G_STEP(0, 2, 20*32, true,  "4");
  G_STEP(1, 0, 21*32, true,  "4");
  G_STEP(2, 1, 22*32, true,  "4");
  G_STEP(0, 2, 23*32, true,  "4");
  G_STEP(1, 0, 0,     false, "4");
  G_STEP(2, 0, 0,     false, "0");
#undef G_STEP
}

// ---------------- QKV projection -> 32x32-FRAGMENT-ORDERED qf/kf/vf ----------------
// qf/kf: per bh, per q32-block, per dh-slice s (4): 512 elems; elem[L*8+j] =
//   X[q32*32 + (L&31)][s*16 + (L>>5)*8 + j]   (A-op for K, B-op for Q; same formula)
// qf carries the C1 scale (fp32, pre-bf16-round).
// vf: per bh, per k32-block, per d (2: dh 32-block), per ks (2: key 16-slice): 512 elems;
//   elem[L*8+j] = V[k32*32 + ks*16 + (L>>5)*8 + j][d*32 + (L&31)]
__global__ __launch_bounds__(256, 3) void qkv_gemm(
    const __bf16* __restrict__ Xq, const __bf16* __restrict__ Xk, const __bf16* __restrict__ Xv,
    const __bf16* __restrict__ Wqb, const __bf16* __restrict__ Wkb, const __bf16* __restrict__ Wvb,
    const float* __restrict__ bq, const float* __restrict__ bk, const float* __restrict__ bv,
    __bf16* __restrict__ qf, __bf16* __restrict__ kf, __bf16* __restrict__ vf)
{
  __shared__ __bf16 lds[3*8192];   // 48 KB
  const int mode = blockIdx.z;
  const __bf16* A = (mode == 0) ? Xq : (mode == 1) ? Xk : Xv;
  const __bf16* W = (mode == 0) ? Wqb : (mode == 1) ? Wkb : Wvb;
  const float* bias = (mode == 0) ? bq : (mode == 1) ? bk : bv;
  const int m0 = blockIdx.y << 7, n0 = blockIdx.x << 7;
  v4f acc[4][4];
  #pragma unroll
  for (int i = 0; i < 4; i++)
    #pragma unroll
    for (int j = 0; j < 4; j++) { v4f z = {0.f,0.f,0.f,0.f}; acc[i][j] = z; }
  gemm128_pipe(A, W, m0, n0, lds, acc);

  const int lane = threadIdx.x & 63;
  const int wave = threadIdx.x >> 6;
  const int wm = (wave >> 1) << 6, wn = (wave & 1) << 6;
  const int col = lane & 15, quad = lane >> 4;
  float bb[4]; int nn[4];
  #pragma unroll
  for (int j = 0; j < 4; j++) { nn[j] = n0 + wn + 16*j + col; bb[j] = bias[nn[j]]; }

  if (mode < 2) {
    __bf16* dst = (mode == 0) ? qf : kf;
    const float sc = (mode == 0) ? C1_ : 1.0f;
    #pragma unroll
    for (int i = 0; i < 4; i++)
      #pragma unroll
      for (int r = 0; r < 4; r++) {
        int m = m0 + wm + 16*i + quad*4 + r;
        int batch = m >> 11, s = m & (S_-1);
        int q32 = s >> 5, s31 = s & 31;
        #pragma unroll
        for (int j = 0; j < 4; j++) {
          int n = nn[j];
          int h = n >> 6, dd = n & 63;
          size_t flat = (((size_t)(batch*H_ + h)*64 + q32)*4 + (dd >> 4))*512
                      + ((((dd >> 3) & 1)*32 + s31) << 3) + (dd & 7);
          dst[flat] = (__bf16)((acc[i][j][r] + bb[j]) * sc);
        }
      }
  } else {
    #pragma unroll
    for (int i = 0; i < 4; i++) {
      int mbase = m0 + wm + 16*i + quad*4;   // +r, r=0..3
      int batch = mbase >> 11, s0 = mbase & (S_-1);
      #pragma unroll
      for (int j = 0; j < 4; j++) {
        int n = nn[j];
        int h = n >> 6, dd = n & 63;
        v4bf pk;
        #pragma unroll
        for (int r = 0; r < 4; r++) pk[r] = (__bf16)(acc[i][j][r] + bb[j]);
        size_t flat = ((((size_t)(batch*H_ + h)*64 + (s0 >> 5))*2 + (dd >> 5))*2 + ((s0 >> 4) & 1))*512
                    + ((((s0 >> 3) & 1)*32 + (dd & 31)) << 3) + (s0 & 7);
        *(v4bf*)(vf + flat) = pk;
      }
    }
  }
}

// ---------------- flash attention: 128 q/block, 4 waves of 32 q, 32x32x16 MFMA ----------------
// LDS-bandwidth fix vs the 16x16 version: a wave owns 32 queries, so only 4 waves re-read
// each K/V LDS tile (32 KB/step vs ~92 KB), and P never touches LDS.  Cross-half exchange
// for the PV B-fragment uses __shfl_xor(.,32) + per-lane select (plain HIP, unambiguous):
// the C/D output has hi-lanes = keys+4; the B-op needs hi-lanes = keys+8.  With
// g_i = {p[2i],p[2i+1]}: u0 = hi? shfl(g2): g0 (= [g0.lo,g2.lo]), u2 = hi? g2: shfl(g0)
// (= [g0.hi,g2.hi]), etc.  Counted-vmcnt pipeline kept: 4 buffers, 2-tile lookahead,
// 4 VMEM/step (2 global_load_lds + 2 em loads), wait vmcnt(4) at top of step.
__global__ __launch_bounds__(256, 2) void attn_kernel(
    const __bf16* __restrict__ qf, const __bf16* __restrict__ kf, const __bf16* __restrict__ vf,
    const __bf16* __restrict__ em, __bf16* __restrict__ ao)
{
  __shared__ __bf16 kv[4][2][2048];   // [buf][K=0/V=1][4 KB]  32 KB total

  const int bh = blockIdx.y;
  const int qt = blockIdx.x;                     // 0..15  (128-query tile)
  const int wave = threadIdx.x >> 6, lane = threadIdx.x & 63;
  const int q5 = lane & 31, hi = lane >> 5;
  const int batch = bh / H_, h = bh % H_;
  const __bf16* qfb = qf + (size_t)bh * (S_*DH_);
  const __bf16* kfb = kf + (size_t)bh * (S_*DH_);
  const __bf16* vfb = vf + (size_t)bh * (S_*DH_);
  const __bf16* emw = em + (size_t)qt*262144 + wave*1024 + lane*16;  // + kt*4096 per step

  // Q fragments (B-op): this wave's 32 queries, 4 dh-slices
  const int q32 = qt*4 + wave;
  v8bf Qb[4];
  #pragma unroll
  for (int s4 = 0; s4 < 4; s4++)
    Qb[s4] = *(const v8bf*)(qfb + ((size_t)q32*4 + s4)*512 + lane*8);

  // staging: each wave stages 1 KB of K and 1 KB of V per step
  const __bf16* gK = kfb + wave*512 + lane*8;
  const __bf16* gV = vfb + wave*512 + lane*8;
  __bf16* kd[4]; __bf16* vd[4];
  #pragma unroll
  for (int b = 0; b < 4; b++) { kd[b] = &kv[b][0][wave*512]; vd[b] = &kv[b][1][wave*512]; }

  f32x16 O0, O1;
  #pragma unroll
  for (int z = 0; z < 16; z++) { O0[z] = 0.f; O1[z] = 0.f; }
  float li = 0.f;

  // ---- pipelined prologue: tiles 0 and 1 ----
  asm volatile("" ::: "memory");
  gload_lds16(gK, kd[0]);
  gload_lds16(gV, vd[0]);
  v8bf e0a = *(const v8bf*)(emw);
  v8bf e0b = *(const v8bf*)(emw + 8);
  asm volatile("" ::: "memory");
  gload_lds16(gK + 2048, kd[1]);
  gload_lds16(gV + 2048, vd[1]);
  v8bf e1a = *(const v8bf*)(emw + 4096);
  v8bf e1b = *(const v8bf*)(emw + 4104);
  v8bf e2a, e2b, e3a, e3b;

#define ATT_STEP(P, EA, EB, NA, NB, ISSUE, WSTR) \
  { \
    asm volatile("s_waitcnt vmcnt(" WSTR ")" ::: "memory"); \
    __builtin_amdgcn_s_barrier(); \
    asm volatile("" ::: "memory"); \
    if (ISSUE) { \
      const int nkt = kt0 + (P) + 2; \
      gload_lds16(gK + (size_t)nkt*2048, kd[((P)+2)&3]); \
      gload_lds16(gV + (size_t)nkt*2048, vd[((P)+2)&3]); \
      NA = *(const v8bf*)(emw + (size_t)nkt*4096); \
      NB = *(const v8bf*)(emw + (size_t)nkt*4096 + 8); \
    } \
    const __bf16* Kb = kv[(P)&3][0]; \
    const __bf16* Vb = kv[(P)&3][1]; \
    f32x16 Sx; \
    _Pragma("unroll") \
    for (int z = 0; z < 16; z++) Sx[z] = 0.f; \
    _Pragma("unroll") \
    for (int s4 = 0; s4 < 4; s4++) { \
      v8bf Ka = *(const v8bf*)(Kb + s4*512 + lane*8); \
      Sx = mfma32(Ka, Qb[s4], Sx); \
    } \
    float p[16]; float rs = 0.f; \
    _Pragma("unroll") \
    for (int r = 0; r < 8; r++) p[r] = exp2f(Sx[r]) * (float)EA[r]; \
    _Pragma("unroll") \
    for (int r = 0; r < 8; r++) p[8+r] = exp2f(Sx[8+r]) * (float)EB[r]; \
    _Pragma("unroll") \
    for (int r = 0; r < 16; r++) rs += p[r]; \
    li += rs; \
    unsigned g0,g1,g2,g3,g4,g5,g6,g7; \
    { union { __bf16 hh[2]; unsigned u; } t_; \
      t_.hh[0]=(__bf16)p[0];  t_.hh[1]=(__bf16)p[1];  g0=t_.u; \
      t_.hh[0]=(__bf16)p[2];  t_.hh[1]=(__bf16)p[3];  g1=t_.u; \
      t_.hh[0]=(__bf16)p[4];  t_.hh[1]=(__bf16)p[5];  g2=t_.u; \
      t_.hh[0]=(__bf16)p[6];  t_.hh[1]=(__bf16)p[7];  g3=t_.u; \
      t_.hh[0]=(__bf16)p[8];  t_.hh[1]=(__bf16)p[9];  g4=t_.u; \
      t_.hh[0]=(__bf16)p[10]; t_.hh[1]=(__bf16)p[11]; g5=t_.u; \
      t_.hh[0]=(__bf16)p[12]; t_.hh[1]=(__bf16)p[13]; g6=t_.u; \
      t_.hh[0]=(__bf16)p[14]; t_.hh[1]=(__bf16)p[15]; g7=t_.u; } \
    unsigned x0 = __shfl_xor(g0, 32), x1 = __shfl_xor(g1, 32); \
    unsigned x2 = __shfl_xor(g2, 32), x3 = __shfl_xor(g3, 32); \
    unsigned x4 = __shfl_xor(g4, 32), x5 = __shfl_xor(g5, 32); \
    unsigned x6 = __shfl_xor(g6, 32), x7 = __shfl_xor(g7, 32); \
    union { unsigned u[4]; v8bf v; } bp0, bp1; \
    bp0.u[0] = hi ? x2 : g0;   /* [g0.lo, g2.lo] keys 0,1 | 8,9   */ \
    bp0.u[1] = hi ? x3 : g1;   /* [g1.lo, g3.lo] keys 2,3 | 10,11 */ \
    bp0.u[2] = hi ? g2 : x0;   /* [g0.hi, g2.hi] keys 4,5 | 12,13 */ \
    bp0.u[3] = hi ? g3 : x1;   /* [g1.hi, g3.hi] keys 6,7 | 14,15 */ \
    bp1.u[0] = hi ? x6 : g4; \
    bp1.u[1] = hi ? x7 : g5; \
    bp1.u[2] = hi ? g6 : x4; \
    bp1.u[3] = hi ? g7 : x5; \
    v8bf Va00 = *(const v8bf*)(Vb + lane*8); \
    v8bf Va01 = *(const v8bf*)(Vb + 512 + lane*8); \
    v8bf Va10 = *(const v8bf*)(Vb + 1024 + lane*8); \
    v8bf Va11 = *(const v8bf*)(Vb + 1536 + lane*8); \
    O0 = mfma32(Va00, bp0.v, O0); \
    O0 = mfma32(Va01, bp1.v, O0); \
    O1 = mfma32(Va10, bp0.v, O1); \
    O1 = mfma32(Va11, bp1.v, O1); \
  }

  #pragma unroll 1
  for (int kt0 = 0; kt0 < 60; kt0 += 4) {
    ATT_STEP(0, e0a, e0b, e2a, e2b, true, "4");
    ATT_STEP(1, e1a, e1b, e3a, e3b, true, "4");
    ATT_STEP(2, e2a, e2b, e0a, e0b, true, "4");
    ATT_STEP(3, e3a, e3b, e1a, e1b, true, "4");
  }
  {
    const int kt0 = 60;
    ATT_STEP(0, e0a, e0b, e2a, e2b, true,  "4");   // kt=60, issues 62
    ATT_STEP(1, e1a, e1b, e3a, e3b, true,  "4");   // kt=61, issues 63
    ATT_STEP(2, e2a, e2b, e0a, e0b, false, "4");   // kt=62
    ATT_STEP(3, e3a, e3b, e1a, e1b, false, "0");   // kt=63: drain
  }
#undef ATT_STEP

  // ---- epilogue ----
  li += __shfl_xor(li, 32);
  float invl = 1.f / li;
  const int qg = qt*128 + wave*32 + q5;
  __bf16* orow = ao + ((size_t)batch*S_ + qg)*D_ + h*DH_;
  #pragma unroll
  for (int g = 0; g < 4; g++) {
    v4bf o0, o1;
    #pragma unroll
    for (int r = 0; r < 4; r++) {
      o0[r] = (__bf16)(O0[g*4+r] * invl);
      o1[r] = (__bf16)(O1[g*4+r] * invl);
    }
    *(v4bf*)(orow + g*8 + hi*4)      = o0;   // dh = 8g + 4hi + r
    *(v4bf*)(orow + 32 + g*8 + hi*4) = o1;   // dh = 32 + 8g + 4hi + r
  }
}

// ---------------- output projection (128x128 tiles): fp32 out ----------------
__global__ __launch_bounds__(256, 3) void out_gemm(
    const __bf16* __restrict__ Ao, const __bf16* __restrict__ Wob,
    const float* __restrict__ bo, float* __restrict__ out)
{
  __shared__ __bf16 lds[3*8192];   // 48 KB
  const int m0 = blockIdx.y << 7, n0 = blockIdx.x << 7;
  v4f acc[4][4];
  #pragma unroll
  for (int i = 0; i < 4; i++)
    #pragma unroll
    for (int j = 0; j < 4; j++) { v4f z = {0.f,0.f,0.f,0.f}; acc[i][j] = z; }
  gemm128_pipe(Ao, Wob, m0, n0, lds, acc);

  const int lane = threadIdx.x & 63;
  const int wave = threadIdx.x >> 6;
  const int wm = (wave >> 1) << 6, wn = (wave & 1) << 6;
  const int col = lane & 15, quad = lane >> 4;
  float bb[4]; int nn[4];
  #pragma unroll
  for (int j = 0; j < 4; j++) { nn[j] = n0 + wn + 16*j + col; bb[j] = bo[nn[j]]; }
  #pragma unroll
  for (int i = 0; i < 4; i++)
    #pragma unroll
    for (int r = 0; r < 4; r++) {
      int m = m0 + wm + 16*i + quad*4 + r;
      #pragma unroll
      for (int j = 0; j < 4; j++)
        out[(size_t)m*D_ + nn[j]] = acc[i][j][r] + bb[j];
    }
}

extern "C" void kernel_launch(void* const* d_in, const int* in_sizes, int n_in,
                              void* d_out, int out_size, void* d_ws, size_t ws_size,
                              hipStream_t stream)
{
  const float* q    = (const float*)d_in[0];
  const float* k    = (const float*)d_in[1];
  const float* v    = (const float*)d_in[2];
  const float* mask = (const float*)d_in[3];
  const float* Wq   = (const float*)d_in[4];
  const float* bq   = (const float*)d_in[5];
  const float* Wk   = (const float*)d_in[6];
  const float* bk   = (const float*)d_in[7];
  const float* Wv   = (const float*)d_in[8];
  const float* bv   = (const float*)d_in[9];
  const float* Wo   = (const float*)d_in[10];
  const float* bo   = (const float*)d_in[11];

  const size_t XN = (size_t)M_ * D_;
  const size_t WN = (size_t)D_ * D_;
  const size_t HN = (size_t)BH_ * S_ * DH_;

  char* ws = (char*)d_ws;
  __bf16* Xq  = (__bf16*)ws;                 ws += XN * 2;
  __bf16* Xk  = (__bf16*)ws;                 ws += XN * 2;
  __bf16* Xv  = (__bf16*)ws;                 ws += XN * 2;
  __bf16* Wqb = (__bf16*)ws;                 ws += WN * 2;
  __bf16* Wkb = (__bf16*)ws;                 ws += WN * 2;
  __bf16* Wvb = (__bf16*)ws;                 ws += WN * 2;
  __bf16* Wob = (__bf16*)ws;                 ws += WN * 2;
  __bf16* qfb = (__bf16*)ws;                 ws += HN * 2;
  __bf16* kfb = (__bf16*)ws;                 ws += HN * 2;
  __bf16* vfb = (__bf16*)ws;                 ws += HN * 2;
  __bf16* aob = (__bf16*)ws;                 ws += XN * 2;
  // em (8.4 MB = 16 qt * 262144 elems) aliases Xq+Xk (12.6 MB) — dead after qkv_gemm;
  // em_kernel runs after it.
  __bf16* emb = Xq;

  convert_kernel<<<dim3(768, 7), 256, 0, stream>>>(
      q, k, v, Wq, Wk, Wv, Wo, Xq, Xk, Xv, Wqb, Wkb, Wvb, Wob);
  qkv_gemm<<<dim3(6, 32, 3), 256, 0, stream>>>(
      Xq, Xk, Xv, Wqb, Wkb, Wvb, bq, bk, bv, qfb, kfb, vfb);
  em_kernel<<<dim3(1024), 256, 0, stream>>>(mask, emb);
  attn_kernel<<<dim3(16, 24), 256, 0, stream>>>(qfb, kfb, vfb, emb, aob);
  out_gemm<<<dim3(6, 32), 256, 0, stream>>>(aob, Wob, bo, (float*)d_out);
}